// Round 1
// baseline (1308.811 us; speedup 1.0000x reference)
//
#include <hip/hip_runtime.h>
#include <hip/hip_fp16.h>

#define TPB 256
#define CAP_L 262144       // cone row cap (|marked| ~ 85K mean)

typedef unsigned int uv4 __attribute__((ext_vector_type(4)));
union H8 { uv4 u; __half2 h2[4]; };

// ---------------- degree count: 10M global atomics into deg[1M] (L2-resident) -----
__global__ __launch_bounds__(TPB) void deg_count(const int* __restrict__ dst,
                                                 int* __restrict__ deg, int E) {
    int i = (blockIdx.x * TPB + threadIdx.x) * 4;
    if (i + 3 < E) {
        int4 d = *(const int4*)(dst + i);
        atomicAdd(&deg[d.x], 1);
        atomicAdd(&deg[d.y], 1);
        atomicAdd(&deg[d.z], 1);
        atomicAdd(&deg[d.w], 1);
    } else {
        for (; i < E; ++i) atomicAdd(&deg[dst[i]], 1);
    }
}

// ---------------- exclusive scan of deg -> rowptr (3-kernel) ----------------
__global__ void scan_blocks(const int* __restrict__ deg, int* __restrict__ rowptr,
                            int* __restrict__ bsum, int n) {
    __shared__ int lds[TPB];
    int i = blockIdx.x * TPB + threadIdx.x;
    int v = (i < n) ? deg[i] : 0;
    lds[threadIdx.x] = v;
    __syncthreads();
#pragma unroll
    for (int off = 1; off < TPB; off <<= 1) {
        int t = (threadIdx.x >= off) ? lds[threadIdx.x - off] : 0;
        __syncthreads();
        lds[threadIdx.x] += t;
        __syncthreads();
    }
    if (i < n) rowptr[i] = lds[threadIdx.x] - v;
    if (threadIdx.x == TPB - 1) bsum[blockIdx.x] = lds[TPB - 1];
}

__global__ void bsum_scan(int* __restrict__ bsum, int nb, int* __restrict__ total) {
    __shared__ int lds[TPB];
    int carry = 0;
    for (int base = 0; base < nb; base += TPB) {
        int i = base + threadIdx.x;
        int v = (i < nb) ? bsum[i] : 0;
        lds[threadIdx.x] = v;
        __syncthreads();
        for (int off = 1; off < TPB; off <<= 1) {
            int t = (threadIdx.x >= off) ? lds[threadIdx.x - off] : 0;
            __syncthreads();
            lds[threadIdx.x] += t;
            __syncthreads();
        }
        int incl = lds[threadIdx.x];
        if (i < nb) bsum[i] = carry + incl - v;
        carry += lds[TPB - 1];
        __syncthreads();
    }
    if (threadIdx.x == 0) *total = carry;
}

// finalize rowptr; init cursor = rowptr; dis = rsqrt(deg+1)
__global__ void scan_add(int* __restrict__ rowptr, const int* __restrict__ bsum,
                         int* __restrict__ deg_cur, float* __restrict__ dis, int n) {
    int i = blockIdx.x * TPB + threadIdx.x;
    if (i >= n) return;
    int d = deg_cur[i];
    int r = rowptr[i] + bsum[blockIdx.x];
    rowptr[i] = r;
    deg_cur[i] = r;                        // becomes cursor, then row-end
    dis[i] = rsqrtf((float)d + 1.0f);
}

// ---------------- exact CSR fill: col[cursor[dst]++] = src ----------------
// scattered 4B writes into 40MB col: partial lines merge in L3 (col fully L3-resident)
__global__ __launch_bounds__(TPB) void csr_scatter(const int* __restrict__ dst,
                                                   const int* __restrict__ src,
                                                   int* __restrict__ cur,
                                                   int* __restrict__ col, int E) {
    int i = (blockIdx.x * TPB + threadIdx.x) * 4;
    if (i + 3 < E) {
        int4 d = *(const int4*)(dst + i);
        int4 s = *(const int4*)(src + i);
        col[atomicAdd(&cur[d.x], 1)] = s.x;
        col[atomicAdd(&cur[d.y], 1)] = s.y;
        col[atomicAdd(&cur[d.z], 1)] = s.z;
        col[atomicAdd(&cur[d.w], 1)] = s.w;
    } else {
        for (; i < E; ++i) col[atomicAdd(&cur[dst[i]], 1)] = src[i];
    }
}
// after this kernel, cur[u] = rowptr[u] + deg[u] = row end

// ---------------- seed: mark idx nodes (tag 1) + enqueue unique ----------------
__global__ void seed_mark_q(const int* __restrict__ idx, int B, int* __restrict__ mark,
                            int* __restrict__ L, int* __restrict__ qq) {
    int t = threadIdx.x;
    if (t < B) {
        int u = idx[t];
        if (atomicCAS(&mark[u], 0, 1) == 0)
            L[atomicAdd(&qq[7], 1)] = u;
    }
}

__global__ void snap_qb(int* __restrict__ qq, int k) { qq[k] = qq[7]; }

// ------- frontier expansion: tier t processes rows [qq[t-2], qq[t-1]) -------------
__global__ __launch_bounds__(TPB) void expand_f(int* __restrict__ L, int* __restrict__ qq,
                                                int tier,
                                                const int* __restrict__ rowptr,
                                                const int* __restrict__ rend,
                                                const int* __restrict__ col,
                                                int* __restrict__ mark) {
    int lo = qq[tier - 2], hi = qq[tier - 1];
    int stride = gridDim.x * blockDim.x;
    for (int r = lo + blockIdx.x * blockDim.x + threadIdx.x; r < hi; r += stride) {
        int u = L[r];
        int e0 = rowptr[u], e1 = rend[u];
        for (int k = e0; k < e1; ++k) {
            int s = col[k];
            if (mark[s] == 0 && atomicCAS(&mark[s], 0, tier) == 0)
                L[atomicAdd(&qq[7], 1)] = s;
        }
    }
}

// ---------------- layer 1 (all nodes): hs = (x*W1)*dis  (fp16x8) ----------------
__global__ void node_l1(const float* __restrict__ x, const float* __restrict__ W1,
                        const float* __restrict__ dis, __half* __restrict__ hs, int n) {
    int i = blockIdx.x * blockDim.x + threadIdx.x;
    if (i >= n) return;
    float xd = x[i] * dis[i];
    float4 w0 = ((const float4*)W1)[0];
    float4 w1 = ((const float4*)W1)[1];
    H8 o;
    o.h2[0] = __floats2half2_rn(xd * w0.x, xd * w0.y);
    o.h2[1] = __floats2half2_rn(xd * w0.z, xd * w0.w);
    o.h2[2] = __floats2half2_rn(xd * w1.x, xd * w1.y);
    o.h2[3] = __floats2half2_rn(xd * w1.z, xd * w1.w);
    ((uv4*)hs)[i] = o.u;
}

// ---------------- fused pull + node transform over rows [0, qq[bidx]) ------------
__global__ void pull_tier(const int* __restrict__ L, const int* __restrict__ qq, int bidx,
                          const int* __restrict__ rowptr, const int* __restrict__ rend,
                          const int* __restrict__ col, const float* __restrict__ dis,
                          const __half* __restrict__ hs_in, const float* __restrict__ bias,
                          const float* __restrict__ W, __half* __restrict__ hs_out) {
    int r = blockIdx.x * blockDim.x + threadIdx.x;
    if (r >= qq[bidx]) return;
    int u = L[r];
    const uv4* hv = (const uv4*)hs_in;
    H8 p; p.u = hv[u];                       // self term
    float2 a0 = __half22float2(p.h2[0]);
    float2 a1 = __half22float2(p.h2[1]);
    float2 a2 = __half22float2(p.h2[2]);
    float2 a3 = __half22float2(p.h2[3]);
    int s = rowptr[u], e = rend[u];
    for (int k = s; k < e; ++k) {
        H8 q; q.u = hv[col[k]];
        float2 b0 = __half22float2(q.h2[0]);
        float2 b1 = __half22float2(q.h2[1]);
        float2 b2 = __half22float2(q.h2[2]);
        float2 b3 = __half22float2(q.h2[3]);
        a0.x += b0.x; a0.y += b0.y; a1.x += b1.x; a1.y += b1.y;
        a2.x += b2.x; a2.y += b2.y; a3.x += b3.x; a3.y += b3.y;
    }
    float d = dis[u];
    float t[8] = {a0.x * d, a0.y * d, a1.x * d, a1.y * d,
                  a2.x * d, a2.y * d, a3.x * d, a3.y * d};
#pragma unroll
    for (int k = 0; k < 8; ++k) {
        float v = t[k] + bias[k];
        t[k] = v > 0.0f ? v : 0.0f;
    }
    float h[8];
#pragma unroll
    for (int j = 0; j < 8; ++j) {
        float acc = 0.0f;
#pragma unroll
        for (int k = 0; k < 8; ++k) acc += t[k] * W[k * 8 + j];
        h[j] = acc * d;
    }
    H8 o;
    o.h2[0] = __floats2half2_rn(h[0], h[1]);
    o.h2[1] = __floats2half2_rn(h[2], h[3]);
    o.h2[2] = __floats2half2_rn(h[4], h[5]);
    o.h2[3] = __floats2half2_rn(h[6], h[7]);
    ((uv4*)hs_out)[u] = o.u;
}

// ---------------- final: out[t][:] = dis*(sum+self) + b4, for the idx nodes ------
__global__ void pull_final(const int* __restrict__ idx, int B,
                           const int* __restrict__ rowptr, const int* __restrict__ rend,
                           const int* __restrict__ col,
                           const float* __restrict__ dis, const __half* __restrict__ hs_in,
                           const float* __restrict__ b4, float* __restrict__ out) {
    int t = blockIdx.x * blockDim.x + threadIdx.x;
    if (t >= B) return;
    int u = idx[t];
    const uv4* hv = (const uv4*)hs_in;
    H8 p; p.u = hv[u];
    float2 a0 = __half22float2(p.h2[0]);
    float2 a1 = __half22float2(p.h2[1]);
    float2 a2 = __half22float2(p.h2[2]);
    float2 a3 = __half22float2(p.h2[3]);
    int s = rowptr[u], e = rend[u];
    for (int k = s; k < e; ++k) {
        H8 q; q.u = hv[col[k]];
        float2 b0 = __half22float2(q.h2[0]);
        float2 b1 = __half22float2(q.h2[1]);
        float2 b2 = __half22float2(q.h2[2]);
        float2 b3 = __half22float2(q.h2[3]);
        a0.x += b0.x; a0.y += b0.y; a1.x += b1.x; a1.y += b1.y;
        a2.x += b2.x; a2.y += b2.y; a3.x += b3.x; a3.y += b3.y;
    }
    float d = dis[u];
    float* op = out + (size_t)t * 8;
    op[0] = a0.x * d + b4[0]; op[1] = a0.y * d + b4[1];
    op[2] = a1.x * d + b4[2]; op[3] = a1.y * d + b4[3];
    op[4] = a2.x * d + b4[4]; op[5] = a2.y * d + b4[5];
    op[6] = a3.x * d + b4[6]; op[7] = a3.y * d + b4[7];
}

extern "C" void kernel_launch(void* const* d_in, const int* in_sizes, int n_in,
                              void* d_out, int out_size, void* d_ws, size_t ws_size,
                              hipStream_t stream) {
    const float* x   = (const float*)d_in[0];
    const int*   ei  = (const int*)d_in[1];
    const int*   idx = (const int*)d_in[2];
    const float* W1  = (const float*)d_in[3];
    const float* b1  = (const float*)d_in[4];
    const float* W2  = (const float*)d_in[5];
    const float* b2  = (const float*)d_in[6];
    const float* W3  = (const float*)d_in[7];
    const float* b3  = (const float*)d_in[8];
    const float* W4  = (const float*)d_in[9];
    const float* b4  = (const float*)d_in[10];

    const int n = in_sizes[0];      // 1,000,000 nodes
    const int E = in_sizes[1] / 2;  // 10,000,000 edges
    const int B = in_sizes[2];      // 64 graphs

    const int* src = ei;
    const int* dst = ei + E;

    // workspace (int elements):
    size_t o_mark = 0;
    size_t o_dis  = o_mark + (size_t)n;
    size_t o_rp   = o_dis  + (size_t)n;
    size_t o_cur  = o_rp   + (size_t)n;          // deg -> cursor -> row-end
    size_t o_hsA  = o_cur  + (size_t)n;
    size_t o_hsB  = o_hsA  + (size_t)n * 4;
    size_t o_L    = o_hsB  + (size_t)n * 4;
    size_t o_col  = o_L    + CAP_L;
    size_t o_sm   = o_col  + (size_t)E;

    int*    mark   = (int*)d_ws + o_mark;
    float*  dis    = (float*)d_ws + o_dis;
    int*    rowptr = (int*)d_ws + o_rp;
    int*    cur    = (int*)d_ws + o_cur;
    __half* hsA    = (__half*)((int*)d_ws + o_hsA);
    __half* hsB    = (__half*)((int*)d_ws + o_hsB);
    int*    L      = (int*)d_ws + o_L;
    int*    col    = (int*)d_ws + o_col;
    int*    bsum1  = (int*)d_ws + o_sm;          // 3907 + pad
    int*    qq     = bsum1 + 4096 + 8;           // [0..4]=tier bounds, [7]=qtail
    int*    scratch= qq + 16;

    const int gnN = (n + TPB - 1) / TPB;                 // 3907
    const int gE4 = (E / 4 + TPB - 1) / TPB;             // 9766
    const int nb2 = CAP_L / TPB;                         // 1024

    // ---- init ----
    (void)hipMemsetAsync(mark, 0, (size_t)n * sizeof(int), stream);
    (void)hipMemsetAsync(cur, 0, (size_t)n * sizeof(int), stream);
    (void)hipMemsetAsync(qq, 0, 16 * sizeof(int), stream);

    // ---- exact CSR build ----
    deg_count<<<gE4, TPB, 0, stream>>>(dst, cur, E);
    scan_blocks<<<gnN, TPB, 0, stream>>>(cur, rowptr, bsum1, n);
    bsum_scan<<<1, TPB, 0, stream>>>(bsum1, gnN, scratch);
    scan_add<<<gnN, TPB, 0, stream>>>(rowptr, bsum1, cur, dis, n);
    csr_scatter<<<gE4, TPB, 0, stream>>>(dst, src, cur, col, E);

    // ---- frontier cone expansion (tiny) ----
    seed_mark_q<<<1, 64, 0, stream>>>(idx, B, mark, L, qq);
    snap_qb<<<1, 1, 0, stream>>>(qq, 1);
    expand_f<<<64, TPB, 0, stream>>>(L, qq, 2, rowptr, cur, col, mark);
    snap_qb<<<1, 1, 0, stream>>>(qq, 2);
    expand_f<<<128, TPB, 0, stream>>>(L, qq, 3, rowptr, cur, col, mark);
    snap_qb<<<1, 1, 0, stream>>>(qq, 3);
    expand_f<<<256, TPB, 0, stream>>>(L, qq, 4, rowptr, cur, col, mark);
    snap_qb<<<1, 1, 0, stream>>>(qq, 4);

    // ---- layers ----
    node_l1<<<gnN, TPB, 0, stream>>>(x, W1, dis, hsA, n);
    pull_tier<<<nb2, TPB, 0, stream>>>(L, qq, 4, rowptr, cur, col, dis, hsA, b1, W2, hsB);
    pull_tier<<<nb2, TPB, 0, stream>>>(L, qq, 3, rowptr, cur, col, dis, hsB, b2, W3, hsA);
    pull_tier<<<nb2, TPB, 0, stream>>>(L, qq, 2, rowptr, cur, col, dis, hsA, b3, W4, hsB);
    pull_final<<<1, 64, 0, stream>>>(idx, B, rowptr, cur, col, dis, hsB, b4, (float*)d_out);
}

// Round 2
// 572.853 us; speedup vs baseline: 2.2847x; 2.2847x over previous
//
#include <hip/hip_runtime.h>
#include <hip/hip_fp16.h>

#define TPB 256
#define BTPB 512           // threads for bucket_csr
#define NBK 256            // bucket index space (dst >> 12); 245 used
#define BNODES 4096        // nodes per bucket
#define CH 6144            // edges per scatter_sort chunk (35 KB LDS -> 4 blocks/CU)
#define CAPB 45056         // fixed bucket capacity (mean 40960 + 20 sigma)
#define CAP_L 262144       // cone row cap (|marked| ~ 85K mean)

typedef unsigned int uv4 __attribute__((ext_vector_type(4)));
union H8 { uv4 u; __half2 h2[4]; };

// ---------------- init: tails[b] = b * CAPB ----------------
__global__ void init_tails(int* __restrict__ tails) {
    tails[threadIdx.x] = threadIdx.x * CAPB;
}

// ------- partition edges into fixed-capacity buckets; LDS counting sort, burst flush ---
// payload: (dstLow12 << 20) | src  (exactly 32 bits; requires n <= 2^20)
__global__ __launch_bounds__(TPB) void scatter_sort(const int* __restrict__ dst,
                                                    const int* __restrict__ src,
                                                    int* __restrict__ tails,
                                                    unsigned* __restrict__ bdata, int nE) {
    __shared__ unsigned      stage[CH];      // 24 KB
    __shared__ unsigned char bkt[CH];        // 6 KB
    __shared__ int cnt[NBK], sstart[NBK], cur[NBK], cbase[NBK];   // 4 KB
    __shared__ int lds[NBK];                 // 1 KB (scan)
    int t = threadIdx.x;
    long base = (long)blockIdx.x * CH;
    int m = (int)(((long)nE - base < CH) ? (nE - base) : CH);
    cnt[t] = 0;
    __syncthreads();
    // pass 1: count
    for (int k = t; k < m; k += TPB)
        atomicAdd(&cnt[__builtin_nontemporal_load(&dst[base + k]) >> 12], 1);
    __syncthreads();
    // exclusive scan cnt -> sstart
    {
        int v = cnt[t];
        lds[t] = v;
        __syncthreads();
        for (int off = 1; off < NBK; off <<= 1) {
            int u = (t >= off) ? lds[t - off] : 0;
            __syncthreads();
            lds[t] += u;
            __syncthreads();
        }
        sstart[t] = lds[t] - v;
        cur[t] = lds[t] - v;
    }
    __syncthreads();
    // pass 2: place into LDS, sorted by bucket
    for (int k = t; k < m; k += TPB) {
        int d = dst[base + k];
        int s = src[base + k];
        int b = d >> 12;
        int pos = atomicAdd(&cur[b], 1);
        stage[pos] = ((unsigned)(d & 4095) << 20) | (unsigned)s;
        bkt[pos] = (unsigned char)b;
    }
    __syncthreads();
    // reserve global runs
    cbase[t] = cnt[t] ? atomicAdd(&tails[t], cnt[t]) : 0;
    __syncthreads();
    // burst flush: consecutive threads -> consecutive dests; lines filled promptly
    for (int k = t; k < m; k += TPB) {
        int b = bkt[k];
        bdata[cbase[b] + (k - sstart[b])] = stage[k];
    }
}

// ---------------- bucket edge-count prefix: P[b] = sum_{b'<b} cnt_b' ----------------
__global__ void bucket_prefix(const int* __restrict__ tails, int* __restrict__ P) {
    __shared__ int lds[NBK];
    int t = threadIdx.x;
    int c = tails[t] - t * CAPB;
    lds[t] = c;
    __syncthreads();
    for (int off = 1; off < NBK; off <<= 1) {
        int u = (t >= off) ? lds[t - off] : 0;
        __syncthreads();
        lds[t] += u;
        __syncthreads();
    }
    P[t] = lds[t] - c;
    if (t == NBK - 1) P[NBK] = lds[t];
}

// ------- per-bucket exact CSR build: LDS degree count + scan + bucket-local fill -------
// One block per bucket. Writes rowptr (gap-free: rend[u] == rowptr[u+1]), dis, col.
__global__ __launch_bounds__(BTPB) void bucket_csr(const unsigned* __restrict__ bdata,
                                                   const int* __restrict__ tails,
                                                   const int* __restrict__ P,
                                                   int* __restrict__ rowptr,
                                                   float* __restrict__ dis,
                                                   int* __restrict__ col, int n) {
    __shared__ int deg[BNODES];    // 16 KB
    __shared__ int off[BNODES];    // 16 KB (becomes cursor in pass 2)
    __shared__ int part[BTPB];     // 2 KB (scan partials)
    int b = blockIdx.x, t = threadIdx.x;
    int base = b << 12;
    for (int j = t; j < BNODES; j += BTPB) deg[j] = 0;
    __syncthreads();
    int e0 = b * CAPB, e1 = tails[b];
    // pass 1: degree count (plain loads: keep lines for pass 2)
    for (int k = e0 + t; k < e1; k += BTPB)
        atomicAdd(&deg[bdata[k] >> 20], 1);
    __syncthreads();
    // scan 4096 degrees: thread t owns [t*8, t*8+8)
    int loc[8];
    int s = 0;
#pragma unroll
    for (int k = 0; k < 8; ++k) { loc[k] = s; s += deg[t * 8 + k]; }
    part[t] = s;
    __syncthreads();
    for (int o = 1; o < BTPB; o <<= 1) {
        int u = (t >= o) ? part[t - o] : 0;
        __syncthreads();
        part[t] += u;
        __syncthreads();
    }
    int pex = part[t] - s;
#pragma unroll
    for (int k = 0; k < 8; ++k) off[t * 8 + k] = pex + loc[k];
    __syncthreads();
    int Pb = P[b];
    // rowptr / dis (rowptr has n+1 entries; node==n falls in last bucket and gets E)
    for (int j = t; j < BNODES; j += BTPB) {
        int node = base + j;
        if (node <= n) {
            rowptr[node] = Pb + off[j];
            if (node < n) dis[node] = rsqrtf((float)deg[j] + 1.0f);
        }
    }
    __syncthreads();   // all reads of off done before cursor mutation
    // pass 2: bucket-local fill (writes land in contiguous ~164KB window -> L2 merges)
    for (int k = e0 + t; k < e1; k += BTPB) {
        unsigned p = __builtin_nontemporal_load(&bdata[k]);
        int j = p >> 20;
        int pos = Pb + atomicAdd(&off[j], 1);
        col[pos] = (int)(p & 0xFFFFFu);
    }
}

// ---------------- seed: mark idx nodes (tag 1) + enqueue unique ----------------
__global__ void seed_mark_q(const int* __restrict__ idx, int B, int* __restrict__ mark,
                            int* __restrict__ L, int* __restrict__ qq) {
    int t = threadIdx.x;
    if (t < B) {
        int u = idx[t];
        if (atomicCAS(&mark[u], 0, 1) == 0)
            L[atomicAdd(&qq[7], 1)] = u;
    }
}

__global__ void snap_qb(int* __restrict__ qq, int k) { qq[k] = qq[7]; }

// ------- frontier expansion: tier t processes rows [qq[t-2], qq[t-1]) -------------
__global__ __launch_bounds__(TPB) void expand_f(int* __restrict__ L, int* __restrict__ qq,
                                                int tier,
                                                const int* __restrict__ rowptr,
                                                const int* __restrict__ col,
                                                int* __restrict__ mark) {
    int lo = qq[tier - 2], hi = qq[tier - 1];
    int stride = gridDim.x * blockDim.x;
    for (int r = lo + blockIdx.x * blockDim.x + threadIdx.x; r < hi; r += stride) {
        int u = L[r];
        int e0 = rowptr[u], e1 = rowptr[u + 1];
        for (int k = e0; k < e1; ++k) {
            int s = col[k];
            if (mark[s] == 0 && atomicCAS(&mark[s], 0, tier) == 0)
                L[atomicAdd(&qq[7], 1)] = s;
        }
    }
}

// ---------------- layer 1 (all nodes): hs = (x*W1)*dis  (fp16x8) ----------------
__global__ void node_l1(const float* __restrict__ x, const float* __restrict__ W1,
                        const float* __restrict__ dis, __half* __restrict__ hs, int n) {
    int i = blockIdx.x * blockDim.x + threadIdx.x;
    if (i >= n) return;
    float xd = x[i] * dis[i];
    float4 w0 = ((const float4*)W1)[0];
    float4 w1 = ((const float4*)W1)[1];
    H8 o;
    o.h2[0] = __floats2half2_rn(xd * w0.x, xd * w0.y);
    o.h2[1] = __floats2half2_rn(xd * w0.z, xd * w0.w);
    o.h2[2] = __floats2half2_rn(xd * w1.x, xd * w1.y);
    o.h2[3] = __floats2half2_rn(xd * w1.z, xd * w1.w);
    ((uv4*)hs)[i] = o.u;
}

// ---------------- fused pull + node transform over rows [0, qq[bidx]) ------------
__global__ void pull_tier(const int* __restrict__ L, const int* __restrict__ qq, int bidx,
                          const int* __restrict__ rowptr, const int* __restrict__ col,
                          const float* __restrict__ dis,
                          const __half* __restrict__ hs_in, const float* __restrict__ bias,
                          const float* __restrict__ W, __half* __restrict__ hs_out) {
    int r = blockIdx.x * blockDim.x + threadIdx.x;
    if (r >= qq[bidx]) return;
    int u = L[r];
    const uv4* hv = (const uv4*)hs_in;
    H8 p; p.u = hv[u];                       // self term
    float2 a0 = __half22float2(p.h2[0]);
    float2 a1 = __half22float2(p.h2[1]);
    float2 a2 = __half22float2(p.h2[2]);
    float2 a3 = __half22float2(p.h2[3]);
    int s = rowptr[u], e = rowptr[u + 1];
    for (int k = s; k < e; ++k) {
        H8 q; q.u = hv[col[k]];
        float2 b0 = __half22float2(q.h2[0]);
        float2 b1 = __half22float2(q.h2[1]);
        float2 b2 = __half22float2(q.h2[2]);
        float2 b3 = __half22float2(q.h2[3]);
        a0.x += b0.x; a0.y += b0.y; a1.x += b1.x; a1.y += b1.y;
        a2.x += b2.x; a2.y += b2.y; a3.x += b3.x; a3.y += b3.y;
    }
    float d = dis[u];
    float t[8] = {a0.x * d, a0.y * d, a1.x * d, a1.y * d,
                  a2.x * d, a2.y * d, a3.x * d, a3.y * d};
#pragma unroll
    for (int k = 0; k < 8; ++k) {
        float v = t[k] + bias[k];
        t[k] = v > 0.0f ? v : 0.0f;
    }
    float h[8];
#pragma unroll
    for (int j = 0; j < 8; ++j) {
        float acc = 0.0f;
#pragma unroll
        for (int k = 0; k < 8; ++k) acc += t[k] * W[k * 8 + j];
        h[j] = acc * d;
    }
    H8 o;
    o.h2[0] = __floats2half2_rn(h[0], h[1]);
    o.h2[1] = __floats2half2_rn(h[2], h[3]);
    o.h2[2] = __floats2half2_rn(h[4], h[5]);
    o.h2[3] = __floats2half2_rn(h[6], h[7]);
    ((uv4*)hs_out)[u] = o.u;
}

// ---------------- final: out[t][:] = dis*(sum+self) + b4, for the idx nodes ------
__global__ void pull_final(const int* __restrict__ idx, int B,
                           const int* __restrict__ rowptr, const int* __restrict__ col,
                           const float* __restrict__ dis, const __half* __restrict__ hs_in,
                           const float* __restrict__ b4, float* __restrict__ out) {
    int t = blockIdx.x * blockDim.x + threadIdx.x;
    if (t >= B) return;
    int u = idx[t];
    const uv4* hv = (const uv4*)hs_in;
    H8 p; p.u = hv[u];
    float2 a0 = __half22float2(p.h2[0]);
    float2 a1 = __half22float2(p.h2[1]);
    float2 a2 = __half22float2(p.h2[2]);
    float2 a3 = __half22float2(p.h2[3]);
    int s = rowptr[u], e = rowptr[u + 1];
    for (int k = s; k < e; ++k) {
        H8 q; q.u = hv[col[k]];
        float2 b0 = __half22float2(q.h2[0]);
        float2 b1 = __half22float2(q.h2[1]);
        float2 b2 = __half22float2(q.h2[2]);
        float2 b3 = __half22float2(q.h2[3]);
        a0.x += b0.x; a0.y += b0.y; a1.x += b1.x; a1.y += b1.y;
        a2.x += b2.x; a2.y += b2.y; a3.x += b3.x; a3.y += b3.y;
    }
    float d = dis[u];
    float* op = out + (size_t)t * 8;
    op[0] = a0.x * d + b4[0]; op[1] = a0.y * d + b4[1];
    op[2] = a1.x * d + b4[2]; op[3] = a1.y * d + b4[3];
    op[4] = a2.x * d + b4[4]; op[5] = a2.y * d + b4[5];
    op[6] = a3.x * d + b4[6]; op[7] = a3.y * d + b4[7];
}

extern "C" void kernel_launch(void* const* d_in, const int* in_sizes, int n_in,
                              void* d_out, int out_size, void* d_ws, size_t ws_size,
                              hipStream_t stream) {
    const float* x   = (const float*)d_in[0];
    const int*   ei  = (const int*)d_in[1];
    const int*   idx = (const int*)d_in[2];
    const float* W1  = (const float*)d_in[3];
    const float* b1  = (const float*)d_in[4];
    const float* W2  = (const float*)d_in[5];
    const float* b2  = (const float*)d_in[6];
    const float* W3  = (const float*)d_in[7];
    const float* b3  = (const float*)d_in[8];
    const float* W4  = (const float*)d_in[9];
    const float* b4  = (const float*)d_in[10];

    const int n = in_sizes[0];      // 1,000,000 nodes (n <= 2^20 for packing)
    const int E = in_sizes[1] / 2;  // 10,000,000 edges
    const int B = in_sizes[2];      // 64 graphs

    const int* src = ei;
    const int* dst = ei + E;

    const int NB = (n + BNODES - 1) / BNODES;            // 245 buckets

    // workspace (int elements):
    size_t o_mark = 0;
    size_t o_dis  = o_mark + (size_t)n;
    size_t o_rp   = o_dis  + (size_t)n;                  // n+1 (+pad)
    size_t o_hsA  = o_rp   + (size_t)n + 8;
    size_t o_L    = o_hsA  + (size_t)n * 4;
    size_t o_col  = o_L    + CAP_L;
    size_t o_bd   = o_col  + (size_t)E;                  // bdata; hsB aliases its base
    size_t o_sm   = o_bd   + (size_t)NB * CAPB;

    int*      mark   = (int*)d_ws + o_mark;
    float*    dis    = (float*)d_ws + o_dis;
    int*      rowptr = (int*)d_ws + o_rp;
    __half*   hsA    = (__half*)((int*)d_ws + o_hsA);
    int*      L      = (int*)d_ws + o_L;
    int*      col    = (int*)d_ws + o_col;
    unsigned* bdata  = (unsigned*)((int*)d_ws + o_bd);
    __half*   hsB    = (__half*)bdata;                   // bdata dead after bucket_csr
    int*      tails  = (int*)d_ws + o_sm;
    int*      P      = tails + NBK + 8;                  // NBK+1 entries
    int*      qq     = P + NBK + 8;                      // [0..4]=tier bounds, [7]=qtail

    const int gnN = (n + TPB - 1) / TPB;                 // 3907
    const int gs  = (int)(((long)E + CH - 1) / CH);      // 1628
    const int nb2 = CAP_L / TPB;                         // 1024

    // ---- init ----
    (void)hipMemsetAsync(mark, 0, (size_t)n * sizeof(int), stream);
    (void)hipMemsetAsync(qq, 0, 16 * sizeof(int), stream);
    init_tails<<<1, NBK, 0, stream>>>(tails);

    // ---- bucket partition (fixed-capacity, LDS counting sort, burst flush) ----
    scatter_sort<<<gs, TPB, 0, stream>>>(dst, src, tails, bdata, E);

    // ---- exact full CSR from buckets (degree+scan+fill, all bucket-local) ----
    bucket_prefix<<<1, NBK, 0, stream>>>(tails, P);
    bucket_csr<<<NB, BTPB, 0, stream>>>(bdata, tails, P, rowptr, dis, col, n);

    // ---- frontier cone expansion (tiny) ----
    seed_mark_q<<<1, 64, 0, stream>>>(idx, B, mark, L, qq);
    snap_qb<<<1, 1, 0, stream>>>(qq, 1);
    expand_f<<<64, TPB, 0, stream>>>(L, qq, 2, rowptr, col, mark);
    snap_qb<<<1, 1, 0, stream>>>(qq, 2);
    expand_f<<<128, TPB, 0, stream>>>(L, qq, 3, rowptr, col, mark);
    snap_qb<<<1, 1, 0, stream>>>(qq, 3);
    expand_f<<<256, TPB, 0, stream>>>(L, qq, 4, rowptr, col, mark);
    snap_qb<<<1, 1, 0, stream>>>(qq, 4);

    // ---- layers ----
    node_l1<<<gnN, TPB, 0, stream>>>(x, W1, dis, hsA, n);
    pull_tier<<<nb2, TPB, 0, stream>>>(L, qq, 4, rowptr, col, dis, hsA, b1, W2, hsB);
    pull_tier<<<nb2, TPB, 0, stream>>>(L, qq, 3, rowptr, col, dis, hsB, b2, W3, hsA);
    pull_tier<<<nb2, TPB, 0, stream>>>(L, qq, 2, rowptr, col, dis, hsA, b3, W4, hsB);
    pull_final<<<1, 64, 0, stream>>>(idx, B, rowptr, col, dis, hsB, b4, (float*)d_out);
}

// Round 3
// 477.967 us; speedup vs baseline: 2.7383x; 1.1985x over previous
//
#include <hip/hip_runtime.h>
#include <hip/hip_fp16.h>

#define TPB 256
#define BTPB 512           // threads for bucket_csr
#define NBK 256            // bucket index space (dst >> 12); 245 used
#define BNODES 4096        // nodes per bucket
#define CH 6144            // edges per scatter_sort chunk (35 KB LDS -> 4 blocks/CU)
#define CAPB 45056         // fixed bucket capacity (mean 40960 + 20 sigma)
#define CAP_L 262144       // cone row cap (|marked| ~ 92K mean)
#define HSTG 27648         // per-half LDS stage capacity (108 KB; mean 20480 + 50 sigma)

typedef unsigned int uv4 __attribute__((ext_vector_type(4)));
union H8 { uv4 u; __half2 h2[4]; };

// ---------------- init: tails[b] = b * CAPB ----------------
__global__ void init_tails(int* __restrict__ tails) {
    tails[threadIdx.x] = threadIdx.x * CAPB;
}

// ------- partition edges into fixed-capacity buckets; LDS counting sort, burst flush ---
// payload: (dstLow12 << 20) | src  (exactly 32 bits; requires n <= 2^20)
__global__ __launch_bounds__(TPB) void scatter_sort(const int* __restrict__ dst,
                                                    const int* __restrict__ src,
                                                    int* __restrict__ tails,
                                                    unsigned* __restrict__ bdata, int nE) {
    __shared__ unsigned      stage[CH];      // 24 KB
    __shared__ unsigned char bkt[CH];        // 6 KB
    __shared__ int cnt[NBK], sstart[NBK], cur[NBK], cbase[NBK];   // 4 KB
    __shared__ int lds[NBK];                 // 1 KB (scan)
    int t = threadIdx.x;
    long base = (long)blockIdx.x * CH;
    int m = (int)(((long)nE - base < CH) ? (nE - base) : CH);
    cnt[t] = 0;
    __syncthreads();
    // pass 1: count
    for (int k = t; k < m; k += TPB)
        atomicAdd(&cnt[__builtin_nontemporal_load(&dst[base + k]) >> 12], 1);
    __syncthreads();
    // exclusive scan cnt -> sstart
    {
        int v = cnt[t];
        lds[t] = v;
        __syncthreads();
        for (int off = 1; off < NBK; off <<= 1) {
            int u = (t >= off) ? lds[t - off] : 0;
            __syncthreads();
            lds[t] += u;
            __syncthreads();
        }
        sstart[t] = lds[t] - v;
        cur[t] = lds[t] - v;
    }
    __syncthreads();
    // pass 2: place into LDS, sorted by bucket
    for (int k = t; k < m; k += TPB) {
        int d = dst[base + k];
        int s = src[base + k];
        int b = d >> 12;
        int pos = atomicAdd(&cur[b], 1);
        stage[pos] = ((unsigned)(d & 4095) << 20) | (unsigned)s;
        bkt[pos] = (unsigned char)b;
    }
    __syncthreads();
    // reserve global runs
    cbase[t] = cnt[t] ? atomicAdd(&tails[t], cnt[t]) : 0;
    __syncthreads();
    // burst flush: consecutive threads -> consecutive dests; lines filled promptly
    for (int k = t; k < m; k += TPB) {
        int b = bkt[k];
        bdata[cbase[b] + (k - sstart[b])] = stage[k];
    }
}

// ---------------- bucket edge-count prefix: P[b] = sum_{b'<b} cnt_b' ----------------
__global__ void bucket_prefix(const int* __restrict__ tails, int* __restrict__ P) {
    __shared__ int lds[NBK];
    int t = threadIdx.x;
    int c = tails[t] - t * CAPB;
    lds[t] = c;
    __syncthreads();
    for (int off = 1; off < NBK; off <<= 1) {
        int u = (t >= off) ? lds[t - off] : 0;
        __syncthreads();
        lds[t] += u;
        __syncthreads();
    }
    P[t] = lds[t] - c;
    if (t == NBK - 1) P[NBK] = lds[t];
}

// ------- per-bucket exact CSR build, LDS-staged burst flush (no write amplification) ---
// One block per bucket. off[]: counts -> prefix -> cursor, in place.
// Two node-halves: filter-place edges into LDS stage at final offsets, flush contiguous.
// Also fuses layer-1: hs[node] = pack(x[node]*dis*W1row).
__global__ __launch_bounds__(BTPB) void bucket_csr(const unsigned* __restrict__ bdata,
                                                   const int* __restrict__ tails,
                                                   const int* __restrict__ P,
                                                   const float* __restrict__ x,
                                                   const float* __restrict__ W1,
                                                   int* __restrict__ rowptr,
                                                   float* __restrict__ dis,
                                                   __half* __restrict__ hs,
                                                   int* __restrict__ col, int n) {
    __shared__ int      off[BNODES];   // 16 KB
    __shared__ int      part[BTPB];    // 2 KB (scan partials)
    __shared__ unsigned stg[HSTG];     // 108 KB
    int b = blockIdx.x, t = threadIdx.x;
    int base = b << 12;
    for (int j = t; j < BNODES; j += BTPB) off[j] = 0;
    __syncthreads();
    int e0 = b * CAPB, e1 = tails[b];
    int m = e1 - e0;
    // pass 1: degree count into off (plain loads: warm L2 for re-reads)
    for (int k = e0 + t; k < e1; k += BTPB)
        atomicAdd(&off[bdata[k] >> 20], 1);
    __syncthreads();
    // in-place scan of 4096 counts: thread t owns [t*8, t*8+8)
    int loc[8];
    int s = 0;
#pragma unroll
    for (int k = 0; k < 8; ++k) { loc[k] = s; s += off[t * 8 + k]; }
    part[t] = s;
    __syncthreads();
    for (int o = 1; o < BTPB; o <<= 1) {
        int u = (t >= o) ? part[t - o] : 0;
        __syncthreads();
        part[t] += u;
        __syncthreads();
    }
    int pex = part[t] - s;
#pragma unroll
    for (int k = 0; k < 8; ++k) off[t * 8 + k] = pex + loc[k];   // own slots only
    __syncthreads();
    int Pb = P[b];
    int hmid = off[2048];              // edges in first node-half (pristine prefix)
    // rowptr / dis / fused layer-1 (deg recovered from prefix differences)
    float4 w0 = ((const float4*)W1)[0];
    float4 w1 = ((const float4*)W1)[1];
    for (int j = t; j < BNODES; j += BTPB) {
        int node = base + j;
        if (node > n) continue;
        rowptr[node] = Pb + off[j];
        if (node < n) {
            int degj = ((j < BNODES - 1) ? off[j + 1] : m) - off[j];
            float dv = rsqrtf((float)degj + 1.0f);
            dis[node] = dv;
            float xd = x[node] * dv;
            H8 o;
            o.h2[0] = __floats2half2_rn(xd * w0.x, xd * w0.y);
            o.h2[1] = __floats2half2_rn(xd * w0.z, xd * w0.w);
            o.h2[2] = __floats2half2_rn(xd * w1.x, xd * w1.y);
            o.h2[3] = __floats2half2_rn(xd * w1.z, xd * w1.w);
            ((uv4*)hs)[node] = o.u;
        }
    }
    __syncthreads();
    // pass 2: two node-halves; stage in LDS at final offsets, then burst flush
#pragma unroll
    for (int h = 0; h < 2; ++h) {
        int sbeg = h ? hmid : 0;
        int send = h ? m : hmid;
        for (int k = e0 + t; k < e1; k += BTPB) {
            unsigned p = bdata[k];
            int j = p >> 20;
            if ((j >> 11) == h) {
                int pos = atomicAdd(&off[j], 1);
                stg[pos - sbeg] = p & 0xFFFFFu;
            }
        }
        __syncthreads();
        int cnt = send - sbeg;
        for (int k = t; k < cnt; k += BTPB)
            col[Pb + sbeg + k] = (int)stg[k];
        __syncthreads();
    }
}

// ---------------- seed: mark idx nodes (tag 1) + enqueue unique ----------------
__global__ void seed_mark_q(const int* __restrict__ idx, int B, int* __restrict__ mark,
                            int* __restrict__ L, int* __restrict__ qq) {
    int t = threadIdx.x;
    if (t < B) {
        int u = idx[t];
        if (atomicCAS(&mark[u], 0, 1) == 0)
            L[atomicAdd(&qq[7], 1)] = u;
    }
}

__global__ void snap_qb(int* __restrict__ qq, int k) { qq[k] = qq[7]; }

// ------- frontier expansion: tier t processes rows [qq[t-2], qq[t-1]) -------------
__global__ __launch_bounds__(TPB) void expand_f(int* __restrict__ L, int* __restrict__ qq,
                                                int tier,
                                                const int* __restrict__ rowptr,
                                                const int* __restrict__ col,
                                                int* __restrict__ mark) {
    int lo = qq[tier - 2], hi = qq[tier - 1];
    int stride = gridDim.x * blockDim.x;
    for (int r = lo + blockIdx.x * blockDim.x + threadIdx.x; r < hi; r += stride) {
        int u = L[r];
        int e0 = rowptr[u], e1 = rowptr[u + 1];
        for (int k = e0; k < e1; ++k) {
            int s = col[k];
            if (mark[s] == 0 && atomicCAS(&mark[s], 0, tier) == 0)
                L[atomicAdd(&qq[7], 1)] = s;
        }
    }
}

// ---------------- fused pull + node transform over rows [0, qq[bidx]) ------------
__global__ void pull_tier(const int* __restrict__ L, const int* __restrict__ qq, int bidx,
                          const int* __restrict__ rowptr, const int* __restrict__ col,
                          const float* __restrict__ dis,
                          const __half* __restrict__ hs_in, const float* __restrict__ bias,
                          const float* __restrict__ W, __half* __restrict__ hs_out) {
    int r = blockIdx.x * blockDim.x + threadIdx.x;
    if (r >= qq[bidx]) return;
    int u = L[r];
    const uv4* hv = (const uv4*)hs_in;
    H8 p; p.u = hv[u];                       // self term
    float2 a0 = __half22float2(p.h2[0]);
    float2 a1 = __half22float2(p.h2[1]);
    float2 a2 = __half22float2(p.h2[2]);
    float2 a3 = __half22float2(p.h2[3]);
    int s = rowptr[u], e = rowptr[u + 1];
    for (int k = s; k < e; ++k) {
        H8 q; q.u = hv[col[k]];
        float2 b0 = __half22float2(q.h2[0]);
        float2 b1 = __half22float2(q.h2[1]);
        float2 b2 = __half22float2(q.h2[2]);
        float2 b3 = __half22float2(q.h2[3]);
        a0.x += b0.x; a0.y += b0.y; a1.x += b1.x; a1.y += b1.y;
        a2.x += b2.x; a2.y += b2.y; a3.x += b3.x; a3.y += b3.y;
    }
    float d = dis[u];
    float t[8] = {a0.x * d, a0.y * d, a1.x * d, a1.y * d,
                  a2.x * d, a2.y * d, a3.x * d, a3.y * d};
#pragma unroll
    for (int k = 0; k < 8; ++k) {
        float v = t[k] + bias[k];
        t[k] = v > 0.0f ? v : 0.0f;
    }
    float h[8];
#pragma unroll
    for (int j = 0; j < 8; ++j) {
        float acc = 0.0f;
#pragma unroll
        for (int k = 0; k < 8; ++k) acc += t[k] * W[k * 8 + j];
        h[j] = acc * d;
    }
    H8 o;
    o.h2[0] = __floats2half2_rn(h[0], h[1]);
    o.h2[1] = __floats2half2_rn(h[2], h[3]);
    o.h2[2] = __floats2half2_rn(h[4], h[5]);
    o.h2[3] = __floats2half2_rn(h[6], h[7]);
    ((uv4*)hs_out)[u] = o.u;
}

// ---------------- final: out[t][:] = dis*(sum+self) + b4, for the idx nodes ------
__global__ void pull_final(const int* __restrict__ idx, int B,
                           const int* __restrict__ rowptr, const int* __restrict__ col,
                           const float* __restrict__ dis, const __half* __restrict__ hs_in,
                           const float* __restrict__ b4, float* __restrict__ out) {
    int t = blockIdx.x * blockDim.x + threadIdx.x;
    if (t >= B) return;
    int u = idx[t];
    const uv4* hv = (const uv4*)hs_in;
    H8 p; p.u = hv[u];
    float2 a0 = __half22float2(p.h2[0]);
    float2 a1 = __half22float2(p.h2[1]);
    float2 a2 = __half22float2(p.h2[2]);
    float2 a3 = __half22float2(p.h2[3]);
    int s = rowptr[u], e = rowptr[u + 1];
    for (int k = s; k < e; ++k) {
        H8 q; q.u = hv[col[k]];
        float2 b0 = __half22float2(q.h2[0]);
        float2 b1 = __half22float2(q.h2[1]);
        float2 b2 = __half22float2(q.h2[2]);
        float2 b3 = __half22float2(q.h2[3]);
        a0.x += b0.x; a0.y += b0.y; a1.x += b1.x; a1.y += b1.y;
        a2.x += b2.x; a2.y += b2.y; a3.x += b3.x; a3.y += b3.y;
    }
    float d = dis[u];
    float* op = out + (size_t)t * 8;
    op[0] = a0.x * d + b4[0]; op[1] = a0.y * d + b4[1];
    op[2] = a1.x * d + b4[2]; op[3] = a1.y * d + b4[3];
    op[4] = a2.x * d + b4[4]; op[5] = a2.y * d + b4[5];
    op[6] = a3.x * d + b4[6]; op[7] = a3.y * d + b4[7];
}

extern "C" void kernel_launch(void* const* d_in, const int* in_sizes, int n_in,
                              void* d_out, int out_size, void* d_ws, size_t ws_size,
                              hipStream_t stream) {
    const float* x   = (const float*)d_in[0];
    const int*   ei  = (const int*)d_in[1];
    const int*   idx = (const int*)d_in[2];
    const float* W1  = (const float*)d_in[3];
    const float* b1  = (const float*)d_in[4];
    const float* W2  = (const float*)d_in[5];
    const float* b2  = (const float*)d_in[6];
    const float* W3  = (const float*)d_in[7];
    const float* b3  = (const float*)d_in[8];
    const float* W4  = (const float*)d_in[9];
    const float* b4  = (const float*)d_in[10];

    const int n = in_sizes[0];      // 1,000,000 nodes (n <= 2^20 for packing)
    const int E = in_sizes[1] / 2;  // 10,000,000 edges
    const int B = in_sizes[2];      // 64 graphs

    const int* src = ei;
    const int* dst = ei + E;

    const int NB = (n + BNODES - 1) / BNODES;            // 245 buckets

    // workspace (int elements):
    size_t o_mark = 0;
    size_t o_dis  = o_mark + (size_t)n;
    size_t o_rp   = o_dis  + (size_t)n;                  // n+1 (+pad)
    size_t o_hsA  = o_rp   + (size_t)n + 8;
    size_t o_L    = o_hsA  + (size_t)n * 4;
    size_t o_col  = o_L    + CAP_L;
    size_t o_bd   = o_col  + (size_t)E;                  // bdata; hsB aliases its base
    size_t o_sm   = o_bd   + (size_t)NB * CAPB;

    int*      mark   = (int*)d_ws + o_mark;
    float*    dis    = (float*)d_ws + o_dis;
    int*      rowptr = (int*)d_ws + o_rp;
    __half*   hsA    = (__half*)((int*)d_ws + o_hsA);
    int*      L      = (int*)d_ws + o_L;
    int*      col    = (int*)d_ws + o_col;
    unsigned* bdata  = (unsigned*)((int*)d_ws + o_bd);
    __half*   hsB    = (__half*)bdata;                   // bdata dead after bucket_csr
    int*      tails  = (int*)d_ws + o_sm;
    int*      P      = tails + NBK + 8;                  // NBK+1 entries
    int*      qq     = P + NBK + 8;                      // [0..4]=tier bounds, [7]=qtail

    const int gs  = (int)(((long)E + CH - 1) / CH);      // 1628
    const int nb2 = CAP_L / TPB;                         // 1024

    // ---- init ----
    (void)hipMemsetAsync(mark, 0, (size_t)n * sizeof(int), stream);
    (void)hipMemsetAsync(qq, 0, 16 * sizeof(int), stream);
    init_tails<<<1, NBK, 0, stream>>>(tails);

    // ---- bucket partition (fixed-capacity, LDS counting sort, burst flush) ----
    scatter_sort<<<gs, TPB, 0, stream>>>(dst, src, tails, bdata, E);

    // ---- exact full CSR from buckets (LDS-staged; fuses dis + layer-1) ----
    bucket_prefix<<<1, NBK, 0, stream>>>(tails, P);
    bucket_csr<<<NB, BTPB, 0, stream>>>(bdata, tails, P, x, W1, rowptr, dis, hsA, col, n);

    // ---- frontier cone expansion (tiny) ----
    seed_mark_q<<<1, 64, 0, stream>>>(idx, B, mark, L, qq);
    snap_qb<<<1, 1, 0, stream>>>(qq, 1);
    expand_f<<<64, TPB, 0, stream>>>(L, qq, 2, rowptr, col, mark);
    snap_qb<<<1, 1, 0, stream>>>(qq, 2);
    expand_f<<<128, TPB, 0, stream>>>(L, qq, 3, rowptr, col, mark);
    snap_qb<<<1, 1, 0, stream>>>(qq, 3);
    expand_f<<<256, TPB, 0, stream>>>(L, qq, 4, rowptr, col, mark);
    snap_qb<<<1, 1, 0, stream>>>(qq, 4);

    // ---- layers ----
    pull_tier<<<nb2, TPB, 0, stream>>>(L, qq, 4, rowptr, col, dis, hsA, b1, W2, hsB);
    pull_tier<<<nb2, TPB, 0, stream>>>(L, qq, 3, rowptr, col, dis, hsB, b2, W3, hsA);
    pull_tier<<<nb2, TPB, 0, stream>>>(L, qq, 2, rowptr, col, dis, hsA, b3, W4, hsB);
    pull_final<<<1, 64, 0, stream>>>(idx, B, rowptr, col, dis, hsB, b4, (float*)d_out);
}